// Round 8
// baseline (315.588 us; speedup 1.0000x reference)
//
#include <hip/hip_runtime.h>

// Linear(int8-weight, block-sparse) -> quantize -> dequantize, as one fp16 MFMA GEMM.
// out[n,o] = dq(q( (x @ (w_q*mask)^T) * w_scale + bias ))
// N=8192 tokens, O=4096, K=4096.
//
// Numerics: w_q*mask are integers in [-127,127] -> exact in fp16; x->fp16
// rounding error << out_scale quant step (validated: absmax 0.0625).
//
// GEMM: m201 8-phase skeleton (2 K-tiles/iter) UNCHANGED from round 7,
// but on v_mfma_f32_32x32x16_f16 (2178 vs 2075 TF pipe, half the MFMA
// instructions, 24 vs 28 ds_read_b128 per wave/K-tile -- phase 4 reads
// nothing, B nb0 fragments stay live in registers c1->c4).
// Per wave: output 128x64 = acc[4 mb][2 nb] of f32x16.
// A frag: row=lane&31 (+mb*32), k=(lane>>5)*8.. ; B frag symmetric on B^T.
// C/D: col=lane&31, row=(reg&3)+8*(reg>>2)+4*(lane>>5)  [m74/m101].
// LDS panes/staging/swizzle identical to round 7: pane [128][64] f16,
// granule swizzle g -> g^(row&7), stage source gs=(tid&7)^((tid>>3)&7),
// VMCNT(2) only at phases 4/8, LGKM8 after 12-read phases.

#define M_TOK 8192
#define O_FEAT 4096
#define K_FEAT 4096

#define BM 256
#define BN 256
#define NITER 32            // 64 K-tiles, 2 per iteration

using f16x8  = __attribute__((ext_vector_type(8))) _Float16;
using f32x4  = __attribute__((ext_vector_type(4))) float;
using f32x16 = __attribute__((ext_vector_type(16))) float;

#define BAR()    asm volatile("s_barrier" ::: "memory")
#define LGKM0()  asm volatile("s_waitcnt lgkmcnt(0)" ::: "memory")
#define LGKM8()  asm volatile("s_waitcnt lgkmcnt(8)" ::: "memory")
#define VMCNT(n) asm volatile("s_waitcnt vmcnt(" #n ")" ::: "memory")
#define MFMA32(a, b, c) __builtin_amdgcn_mfma_f32_32x32x16_f16((a), (b), (c), 0, 0, 0)

// ---------------- fp32 -> fp16 conversion of activations ----------------
__global__ __launch_bounds__(256) void cvt_x_kernel(const float* __restrict__ x,
                                                    _Float16* __restrict__ xf) {
    size_t i = ((size_t)blockIdx.x * 256 + threadIdx.x) * 8;
    float4 v0 = *reinterpret_cast<const float4*>(x + i);
    float4 v1 = *reinterpret_cast<const float4*>(x + i + 4);
    f16x8 h;
    h[0] = (_Float16)v0.x; h[1] = (_Float16)v0.y;
    h[2] = (_Float16)v0.z; h[3] = (_Float16)v0.w;
    h[4] = (_Float16)v1.x; h[5] = (_Float16)v1.y;
    h[6] = (_Float16)v1.z; h[7] = (_Float16)v1.w;
    *reinterpret_cast<f16x8*>(xf + i) = h;
}

// ------------- fuse block mask into fp16 weights (exact ints) -----------
__global__ __launch_bounds__(256) void cvt_w_kernel(const float* __restrict__ wq,
                                                    const int* __restrict__ mask,
                                                    _Float16* __restrict__ wf) {
    size_t i = ((size_t)blockIdx.x * 256 + threadIdx.x) * 8;  // 8 weights = 2 mask blocks
    float4 v0 = *reinterpret_cast<const float4*>(wq + i);
    float4 v1 = *reinterpret_cast<const float4*>(wq + i + 4);
    int2 mv = *reinterpret_cast<const int2*>(mask + i / 4);
    float m0 = mv.x ? 1.0f : 0.0f;
    float m1 = mv.y ? 1.0f : 0.0f;
    f16x8 h;
    h[0] = (_Float16)(v0.x * m0); h[1] = (_Float16)(v0.y * m0);
    h[2] = (_Float16)(v0.z * m0); h[3] = (_Float16)(v0.w * m0);
    h[4] = (_Float16)(v1.x * m1); h[5] = (_Float16)(v1.y * m1);
    h[6] = (_Float16)(v1.z * m1); h[7] = (_Float16)(v1.w * m1);
    *reinterpret_cast<f16x8*>(wf + i) = h;
}

// ---------------- 256x256 8-phase fp16 MFMA GEMM (32x32x16) -------------
// A [8192][4096] f16 row-major, B [4096][4096] f16 row-major (B^T GEMM).
// LDS byte layout: mat*65536 + buf*32768 + mhalf*16384 + row*128 + swz(col).
__global__ __launch_bounds__(512, 2) void gemm_kernel(const _Float16* __restrict__ A,
                                                      const _Float16* __restrict__ B,
                                                      const float* __restrict__ bias,
                                                      const float* __restrict__ wsp,
                                                      const float* __restrict__ osp,
                                                      float* __restrict__ C) {
    __shared__ __align__(16) unsigned char smem[131072];
    char* smc = (char*)smem;

    const int tid  = threadIdx.x;
    const int lane = tid & 63;
    const int w    = tid >> 6;      // 0..7
    const int wm   = w >> 2;        // 0..1  (M half)
    const int wn   = w & 3;         // 0..3  (N quarter)
    const int r31  = lane & 31;     // fragment row (A) / col (B,C)
    const int kg   = lane >> 5;     // 0..1  k-granule (8 f16)

    const int bm = blockIdx.x >> 4; // 32 M-tiles
    const int bn = blockIdx.x & 15; // 16 N-tiles

    // ---- read bases: granule swizzle g=(kstep<<1|kg) -> g^(row&7) ----
    const int m7 = r31 & 7;
    int koff[4];
#pragma unroll
    for (int ks = 0; ks < 4; ++ks)
        koff[ks] = ((((ks << 1) | kg) ^ m7) << 4);
    const char* aBase = smc + wm * 16384 + r31 * 128;
    const char* bBase = smc + 65536 + (wn >> 1) * 16384 + (wn & 1) * 8192 + r31 * 128;

    // ---- stage geometry: linear LDS dst, inverse-swizzled global src ----
    const int gs = (tid & 7) ^ ((tid >> 3) & 7);   // source 16B granule
    const _Float16* pAsrc = A + (size_t)(bm * BM + (tid >> 3)) * K_FEAT + gs * 8;
    const _Float16* pBsrc = B + (size_t)(bn * BN + (tid >> 3)) * K_FEAT + gs * 8;
    char* dstT = smc + tid * 16;

    auto gload = [&](const _Float16* src, char* dst) {
        __builtin_amdgcn_global_load_lds(
            (const __attribute__((address_space(1))) void*)(const void*)src,
            (__attribute__((address_space(3))) void*)(void*)dst, 16, 0, 0);
    };
    auto stgA = [&](int buf, int mh, int kElem) {   // one A pane = 2 gloads
#pragma unroll
        for (int j = 0; j < 2; ++j)
            gload(pAsrc + (size_t)(mh * 128 + j * 64) * K_FEAT + kElem,
                  dstT + buf * 32768 + mh * 16384 + j * 8192);
    };
    auto stgB = [&](int buf, int mh, int kElem) {   // one B pane = 2 gloads
#pragma unroll
        for (int j = 0; j < 2; ++j)
            gload(pBsrc + (size_t)(mh * 128 + j * 64) * K_FEAT + kElem,
                  dstT + 65536 + buf * 32768 + mh * 16384 + j * 8192);
    };

    auto rdA = [&](int mb, int ks, int buf) -> f16x8 {
        return *reinterpret_cast<const f16x8*>(aBase + buf * 32768 + mb * 4096 + koff[ks]);
    };
    auto rdB = [&](int nb, int ks, int buf) -> f16x8 {
        return *reinterpret_cast<const f16x8*>(bBase + buf * 32768 + nb * 4096 + koff[ks]);
    };

    f32x16 acc[4][2] = {};
    f16x8 aR[8], bv0[4], bv1[4];

#define RD_A2(MB, BUF) _Pragma("unroll") for (int mi = 0; mi < 2; ++mi) \
    _Pragma("unroll") for (int ks = 0; ks < 4; ++ks) aR[mi * 4 + ks] = rdA((MB) + mi, ks, BUF)
#define RD_B(DST, NB, BUF) _Pragma("unroll") for (int ks = 0; ks < 4; ++ks) DST[ks] = rdB((NB), ks, BUF)
#define QUAD(MB, NB, BV) do { _Pragma("unroll") for (int mi = 0; mi < 2; ++mi) \
    _Pragma("unroll") for (int ks = 0; ks < 4; ++ks) \
        acc[(MB) + mi][(NB)] = MFMA32(aR[mi * 4 + ks], BV[ks], acc[(MB) + mi][(NB)]); } while (0)
#define PRIO1() __builtin_amdgcn_s_setprio(1)
#define PRIO0() __builtin_amdgcn_s_setprio(0)

    // ---- prologue: K-tile0 panes (8 loads) + A(1,mh0) (2) ----
    stgA(0, 0, 0); stgA(0, 1, 0); stgB(0, 0, 0); stgB(0, 1, 0);
    stgA(1, 0, 64);
    VMCNT(2);       // K-tile0 landed; A(1,mh0) in flight
    BAR();

    size_t kOff = 0;     // elem K-offset of s0 = 2t
    for (int t = 0; t < NITER; ++t) {
        const bool more = (t + 1 < NITER);

        // ================= K-tile s0 (buf 0) =================
        // c1: 12 reads (A mb01 + B nb0); stage A(s1,mh1)->b1
        RD_A2(0, 0); RD_B(bv0, 0, 0);
        stgA(1, 1, kOff + 64);
        LGKM8(); BAR(); LGKM0();
        PRIO1(); QUAD(0, 0, bv0); PRIO0(); BAR();

        // c2: 4 reads (B nb1); stage B(s1,mh0)->b1
        RD_B(bv1, 1, 0);
        stgB(1, 0, kOff + 64);
        BAR(); LGKM0();
        PRIO1(); QUAD(0, 1, bv1); PRIO0(); BAR();

        // c3: 8 reads (A mb23); stage B(s1,mh1)->b1
        RD_A2(2, 0);
        stgB(1, 1, kOff + 64);
        BAR(); LGKM0();
        PRIO1(); QUAD(2, 1, bv1); PRIO0(); BAR();

        // c4: 0 reads (bv0, aR mb23 live); stage A(s0+2,mh0)->b0; publish s1
        if (more) stgA(0, 0, kOff + 128);
        BAR(); LGKM0();
        PRIO1(); QUAD(2, 0, bv0); PRIO0();
        if (more) { VMCNT(2); } else { VMCNT(0); }
        BAR();

        // ================= K-tile s1 (buf 1) =================
        // c5: 12 reads; stage A(s0+2,mh1)->b0
        RD_A2(0, 1); RD_B(bv0, 0, 1);
        if (more) stgA(0, 1, kOff + 128);
        LGKM8(); BAR(); LGKM0();
        PRIO1(); QUAD(0, 0, bv0); PRIO0(); BAR();

        // c6: 4 reads; stage B(s0+2,mh0)->b0
        RD_B(bv1, 1, 1);
        if (more) stgB(0, 0, kOff + 128);
        BAR(); LGKM0();
        PRIO1(); QUAD(0, 1, bv1); PRIO0(); BAR();

        // c7: 8 reads; stage B(s0+2,mh1)->b0
        RD_A2(2, 1);
        if (more) stgB(0, 1, kOff + 128);
        BAR(); LGKM0();
        PRIO1(); QUAD(2, 1, bv1); PRIO0(); BAR();

        // c8: 0 reads; stage A(s0+3,mh0)->b1; publish s0+2
        if (more) stgA(1, 0, kOff + 192);
        BAR(); LGKM0();
        PRIO1(); QUAD(2, 0, bv0); PRIO0();
        if (more) { VMCNT(2); }
        BAR();

        kOff += 128;
    }

    // ---------------- fused epilogue: scale + bias + quant + dequant ----
    // C/D 32x32: col = lane&31, row = (reg&3) + 8*(reg>>2) + 4*(lane>>5)
    const float wscale = wsp[0];
    const float oscale = osp[0];
    const int row0 = bm * BM + wm * 128;
    const int col0 = bn * BN + wn * 64;
#pragma unroll
    for (int nb = 0; nb < 2; ++nb) {
        const int col = col0 + nb * 32 + r31;
        const float bc = bias[col];
#pragma unroll
        for (int mb = 0; mb < 4; ++mb) {
#pragma unroll
            for (int reg = 0; reg < 16; ++reg) {
                const int row = row0 + mb * 32 + (reg & 3) + 8 * (reg >> 2) + 4 * kg;
                float y = acc[mb][nb][reg] * wscale + bc;
                float q = rintf(y / oscale);          // round-half-even, matches jnp.round
                q = fminf(fmaxf(q, -128.0f), 127.0f);
                C[(size_t)row * O_FEAT + col] = q * oscale;
            }
        }
    }
#undef RD_A2
#undef RD_B
#undef QUAD
#undef PRIO1
#undef PRIO0
}

extern "C" void kernel_launch(void* const* d_in, const int* in_sizes, int n_in,
                              void* d_out, int out_size, void* d_ws, size_t ws_size,
                              hipStream_t stream) {
    const float* x        = (const float*)d_in[0];  // [8192,4096] fp32
    const float* wq       = (const float*)d_in[1];  // [4096,4096] fp32 (int8 values)
    const float* bias     = (const float*)d_in[2];  // [4096]
    const float* w_scale  = (const float*)d_in[3];  // scalar
    const float* out_scale= (const float*)d_in[4];  // scalar
    const int*   mask     = (const int*)d_in[5];    // [4096,1024] int32
    float* out = (float*)d_out;

    _Float16* xf = (_Float16*)d_ws;                                        // 64 MiB
    _Float16* wf = (_Float16*)((char*)d_ws + (size_t)M_TOK * K_FEAT * 2);  // +32 MiB

    cvt_x_kernel<<<(M_TOK * (size_t)K_FEAT) / 8 / 256, 256, 0, stream>>>(x, xf);
    cvt_w_kernel<<<(O_FEAT * (size_t)K_FEAT) / 8 / 256, 256, 0, stream>>>(wq, mask, wf);

    // (8192/256) x (4096/256) = 32*16 = 512 blocks, 512 threads
    gemm_kernel<<<dim3((M_TOK / BM) * (O_FEAT / BN)), 512, 0, stream>>>(
        xf, wf, bias, w_scale, out_scale, out);
}